// Round 1
// baseline (531.182 us; speedup 1.0000x reference)
//
#include <hip/hip_runtime.h>
#include <hip/hip_bf16.h>
#include <math.h>

// GINEConv layer:
//   e    = edge_attr @ We + be            [E,64]
//   msg  = relu(x[src] + e)               [E,64]
//   aggr = segment_sum(msg, dst, N)       [N,64]
//   h    = x + aggr
//   h    = gelu_exact(h @ W1 + b1)
//   out  = h @ W2 + b2                    [N,64]

#define DIM 64

// One wave (64 lanes) per edge. Lane d owns output dim d.
// We column (16 floats) + be[d] live in registers across the grid-stride loop.
__global__ __launch_bounds__(256) void gine_edge_kernel(
    const float* __restrict__ x,      // [N,64]
    const int*   __restrict__ ei,     // [2,E]  row0=src, row1=dst
    const float* __restrict__ ea,     // [E,16]
    const float* __restrict__ We,     // [16,64]
    const float* __restrict__ be,     // [64]
    float*       __restrict__ aggr,   // [N,64]
    int E)
{
    const int lane = threadIdx.x & 63;
    const int wid  = (int)((blockIdx.x * blockDim.x + threadIdx.x) >> 6);
    const int nw   = (int)((gridDim.x * blockDim.x) >> 6);

    float w[16];
#pragma unroll
    for (int k = 0; k < 16; ++k) w[k] = We[k * DIM + lane];
    const float bias = be[lane];

    for (int e = wid; e < E; e += nw) {
        const int s = ei[e];
        const int d = ei[E + e];
        // lanes 0..15 load the 16 edge features; broadcast via shfl
        float eav = (lane < 16) ? ea[(long long)e * 16 + lane] : 0.0f;
        float acc = bias;
#pragma unroll
        for (int k = 0; k < 16; ++k) {
            acc = fmaf(__shfl(eav, k, 64), w[k], acc);
        }
        const float xv = x[(long long)s * DIM + lane];
        const float m  = fmaxf(xv + acc, 0.0f);
        atomicAdd(&aggr[(long long)d * DIM + lane], m);
    }
}

// One wave per node. W1/W2 columns (64 regs each) per-lane, h broadcast via shfl.
__global__ __launch_bounds__(256) void gine_node_kernel(
    const float* __restrict__ x,      // [N,64]
    const float* __restrict__ aggr,   // [N,64]
    const float* __restrict__ W1,     // [64,64]
    const float* __restrict__ b1,     // [64]
    const float* __restrict__ W2,     // [64,64]
    const float* __restrict__ b2,     // [64]
    float*       __restrict__ out,    // [N,64]
    int N)
{
    const int lane = threadIdx.x & 63;
    const int wid  = (int)((blockIdx.x * blockDim.x + threadIdx.x) >> 6);
    const int nw   = (int)((gridDim.x * blockDim.x) >> 6);

    float w1[DIM], w2[DIM];
#pragma unroll
    for (int k = 0; k < DIM; ++k) w1[k] = W1[k * DIM + lane];
#pragma unroll
    for (int k = 0; k < DIM; ++k) w2[k] = W2[k * DIM + lane];
    const float bb1 = b1[lane];
    const float bb2 = b2[lane];

    for (int n = wid; n < N; n += nw) {
        const float h = x[(long long)n * DIM + lane] + aggr[(long long)n * DIM + lane];

        float a = bb1;
#pragma unroll
        for (int k = 0; k < DIM; ++k) a = fmaf(__shfl(h, k, 64), w1[k], a);

        // exact GELU (matches torch nn.GELU default / jax approximate=False)
        const float g = 0.5f * a * (1.0f + erff(a * 0.70710678118654752f));

        float o = bb2;
#pragma unroll
        for (int k = 0; k < DIM; ++k) o = fmaf(__shfl(g, k, 64), w2[k], o);

        out[(long long)n * DIM + lane] = o;
    }
}

extern "C" void kernel_launch(void* const* d_in, const int* in_sizes, int n_in,
                              void* d_out, int out_size, void* d_ws, size_t ws_size,
                              hipStream_t stream) {
    const float* x   = (const float*)d_in[0];
    const int*   ei  = (const int*)d_in[1];
    const float* ea  = (const float*)d_in[2];
    const float* We  = (const float*)d_in[3];
    const float* be  = (const float*)d_in[4];
    const float* W1  = (const float*)d_in[5];
    const float* b1  = (const float*)d_in[6];
    const float* W2  = (const float*)d_in[7];
    const float* b2  = (const float*)d_in[8];

    const int N = in_sizes[0] / DIM;
    const int E = in_sizes[1] / 2;

    float* aggr = (float*)d_ws;                 // [N,64] scratch
    const size_t aggr_bytes = (size_t)N * DIM * sizeof(float);

    hipMemsetAsync(aggr, 0, aggr_bytes, stream);

    gine_edge_kernel<<<2048, 256, 0, stream>>>(x, ei, ea, We, be, aggr, E);

    gine_node_kernel<<<1024, 256, 0, stream>>>(x, aggr, W1, b1, W2, b2,
                                               (float*)d_out, N);
}

// Round 2
// 427.192 us; speedup vs baseline: 1.2434x; 1.2434x over previous
//
#include <hip/hip_runtime.h>
#include <hip/hip_bf16.h>
#include <math.h>

// GINEConv layer:
//   e    = edge_attr @ We + be            [E,64]
//   msg  = relu(x[src] + e)               [E,64]
//   aggr = segment_sum(msg, dst, N)       [N,64]
//   h    = x + aggr
//   h    = gelu_exact(h @ W1 + b1)
//   out  = h @ W2 + b2                    [N,64]

#define DIM 64

// One wave processes 4 edges per iteration. Lane d owns output dim d.
// - edge indices: uniform scalar loads (forced via readfirstlane)
// - ea: 4 rows x 16 floats = 64 values = one coalesced load, one value/lane,
//   broadcast to all lanes via __shfl
// - x[src]: 4 independent coalesced 256B gathers in flight
// - scatter: hardware global_atomic_add_f32 via unsafeAtomicAdd
__global__ __launch_bounds__(256) void gine_edge_kernel(
    const float* __restrict__ x,      // [N,64]
    const int*   __restrict__ ei,     // [2,E]  row0=src, row1=dst
    const float* __restrict__ ea,     // [E,16]
    const float* __restrict__ We,     // [16,64]
    const float* __restrict__ be,     // [64]
    float*       __restrict__ aggr,   // [N,64]
    int E)
{
    const int lane = threadIdx.x & 63;
    const int wid  = (int)((blockIdx.x * blockDim.x + threadIdx.x) >> 6);
    const int nw   = (int)((gridDim.x * blockDim.x) >> 6);

    float w[16];
#pragma unroll
    for (int k = 0; k < 16; ++k) w[k] = We[k * DIM + lane];
    const float bias = be[lane];

    const int nquad = E >> 2;
    for (int q = wid; q < nquad; q += nw) {
        // wave-uniform edge-group base -> scalar loads for indices
        const int e0 = __builtin_amdgcn_readfirstlane(q << 2);

        const int s0 = ei[e0 + 0], s1 = ei[e0 + 1];
        const int s2 = ei[e0 + 2], s3 = ei[e0 + 3];
        const int d0 = ei[E + e0 + 0], d1 = ei[E + e0 + 1];
        const int d2 = ei[E + e0 + 2], d3 = ei[E + e0 + 3];

        // 4 ea rows in one coalesced 256B load: lane l holds ea[e0 + l/16][l%16]
        const float eav = ea[(size_t)e0 * 16 + lane];

        // 4 independent gathers (MLP)
        const float xv0 = x[(size_t)s0 * DIM + lane];
        const float xv1 = x[(size_t)s1 * DIM + lane];
        const float xv2 = x[(size_t)s2 * DIM + lane];
        const float xv3 = x[(size_t)s3 * DIM + lane];

        float a0 = bias, a1 = bias, a2 = bias, a3 = bias;
#pragma unroll
        for (int k = 0; k < 16; ++k) {
            a0 = fmaf(__shfl(eav, k,      64), w[k], a0);
            a1 = fmaf(__shfl(eav, 16 + k, 64), w[k], a1);
            a2 = fmaf(__shfl(eav, 32 + k, 64), w[k], a2);
            a3 = fmaf(__shfl(eav, 48 + k, 64), w[k], a3);
        }

        unsafeAtomicAdd(&aggr[(size_t)d0 * DIM + lane], fmaxf(xv0 + a0, 0.0f));
        unsafeAtomicAdd(&aggr[(size_t)d1 * DIM + lane], fmaxf(xv1 + a1, 0.0f));
        unsafeAtomicAdd(&aggr[(size_t)d2 * DIM + lane], fmaxf(xv2 + a2, 0.0f));
        unsafeAtomicAdd(&aggr[(size_t)d3 * DIM + lane], fmaxf(xv3 + a3, 0.0f));
    }

    // tail (E not divisible by 4)
    for (int e = (nquad << 2) + wid; e < E; e += nw) {
        const int s = ei[e];
        const int d = ei[E + e];
        float eav = (lane < 16) ? ea[(size_t)e * 16 + lane] : 0.0f;
        float acc = bias;
#pragma unroll
        for (int k = 0; k < 16; ++k) acc = fmaf(__shfl(eav, k, 64), w[k], acc);
        const float xv = x[(size_t)s * DIM + lane];
        unsafeAtomicAdd(&aggr[(size_t)d * DIM + lane], fmaxf(xv + acc, 0.0f));
    }
}

// One wave per node. W1/W2 columns in registers; h/g broadcast via
// uniform-address ds_read_b128 (16 reads/layer) instead of 64 bpermutes.
// 4 independent FMA chains per layer.
__global__ __launch_bounds__(256) void gine_node_kernel(
    const float* __restrict__ x,      // [N,64]
    const float* __restrict__ aggr,   // [N,64]
    const float* __restrict__ W1,     // [64,64]
    const float* __restrict__ b1,     // [64]
    const float* __restrict__ W2,     // [64,64]
    const float* __restrict__ b2,     // [64]
    float*       __restrict__ out,    // [N,64]
    int N)
{
    __shared__ float hbuf[4][DIM];    // one 64-float slice per wave

    const int lane  = threadIdx.x & 63;
    const int wslot = threadIdx.x >> 6;     // wave within block (0..3)
    const int wid   = (int)((blockIdx.x * blockDim.x + threadIdx.x) >> 6);
    const int nw    = (int)((gridDim.x * blockDim.x) >> 6);

    float w1[DIM], w2[DIM];
#pragma unroll
    for (int k = 0; k < DIM; ++k) w1[k] = W1[k * DIM + lane];
#pragma unroll
    for (int k = 0; k < DIM; ++k) w2[k] = W2[k * DIM + lane];
    const float bb1 = b1[lane];
    const float bb2 = b2[lane];

    for (int n = wid; n < N; n += nw) {
        const size_t idx = (size_t)n * DIM + lane;
        const float h = x[idx] + aggr[idx];

        // layer 1: a = h @ W1 + b1
        hbuf[wslot][lane] = h;              // wave-private slice, in-order LDS
        float a0 = bb1, a1 = 0.0f, a2 = 0.0f, a3 = 0.0f;
#pragma unroll
        for (int k4 = 0; k4 < 16; ++k4) {
            const float4 hv = *reinterpret_cast<const float4*>(&hbuf[wslot][k4 * 4]);
            a0 = fmaf(hv.x, w1[4 * k4 + 0], a0);
            a1 = fmaf(hv.y, w1[4 * k4 + 1], a1);
            a2 = fmaf(hv.z, w1[4 * k4 + 2], a2);
            a3 = fmaf(hv.w, w1[4 * k4 + 3], a3);
        }
        const float a = (a0 + a1) + (a2 + a3);

        // exact GELU
        const float g = 0.5f * a * (1.0f + erff(a * 0.70710678118654752f));

        // layer 2: out = g @ W2 + b2
        hbuf[wslot][lane] = g;              // same wave: LDS ops ordered
        float o0 = bb2, o1 = 0.0f, o2 = 0.0f, o3 = 0.0f;
#pragma unroll
        for (int k4 = 0; k4 < 16; ++k4) {
            const float4 gv = *reinterpret_cast<const float4*>(&hbuf[wslot][k4 * 4]);
            o0 = fmaf(gv.x, w2[4 * k4 + 0], o0);
            o1 = fmaf(gv.y, w2[4 * k4 + 1], o1);
            o2 = fmaf(gv.z, w2[4 * k4 + 2], o2);
            o3 = fmaf(gv.w, w2[4 * k4 + 3], o3);
        }
        out[idx] = (o0 + o1) + (o2 + o3);
    }
}

extern "C" void kernel_launch(void* const* d_in, const int* in_sizes, int n_in,
                              void* d_out, int out_size, void* d_ws, size_t ws_size,
                              hipStream_t stream) {
    const float* x   = (const float*)d_in[0];
    const int*   ei  = (const int*)d_in[1];
    const float* ea  = (const float*)d_in[2];
    const float* We  = (const float*)d_in[3];
    const float* be  = (const float*)d_in[4];
    const float* W1  = (const float*)d_in[5];
    const float* b1  = (const float*)d_in[6];
    const float* W2  = (const float*)d_in[7];
    const float* b2  = (const float*)d_in[8];

    const int N = in_sizes[0] / DIM;
    const int E = in_sizes[1] / 2;

    float* aggr = (float*)d_ws;                 // [N,64] scratch
    const size_t aggr_bytes = (size_t)N * DIM * sizeof(float);

    hipMemsetAsync(aggr, 0, aggr_bytes, stream);

    gine_edge_kernel<<<2048, 256, 0, stream>>>(x, ei, ea, We, be, aggr, E);

    gine_node_kernel<<<2048, 256, 0, stream>>>(x, aggr, W1, b1, W2, b2,
                                               (float*)d_out, N);
}